// Round 1
// baseline (371.882 us; speedup 1.0000x reference)
//
#include <hip/hip_runtime.h>
#include <hip/hip_bf16.h>

// AttnDecoder: B=2, Lq=Lkv=2048, E=1024, H=16, D=64, scale = 0.125/sqrt(2).
// Pipeline (all bf16 MFMA, fp32 accum):
//   cast3: q,k,v fp32 -> bf16 row-major           [ws +0 .. +24MB]
//   wtrans: Wq,Wk,Wv -> bf16 W^T (N x K); Wo -> permuted W^T folding head-merge [ws +24 .. +32MB]
//   gemm<0> (z=0..2): X @ W -> head-split Qh,Kh [bh][l][c], VhT [bh][c][l] [ws +32 .. +56MB]
//   attn: flash attention per (bh, 128-row q block) -> Oh [bh][l][c]  [ws +0 (over dead casts)]
//   gemm<1>: Oh (permutation folded into A addressing) @ WoT' -> d_out fp32
// Workspace required: 56 MB.

typedef __attribute__((ext_vector_type(8))) short short8;   // 8 x bf16 (4 VGPR)
typedef __attribute__((ext_vector_type(4))) float f32x4;    // MFMA accumulator
typedef __hip_bfloat16 bf16;

#define GLD16(g, l) __builtin_amdgcn_global_load_lds( \
    (const __attribute__((address_space(1))) void*)(g), \
    (__attribute__((address_space(3))) void*)(l), 16, 0, 0)

__device__ __forceinline__ f32x4 mfma16(short8 a, short8 b, f32x4 c) {
  return __builtin_amdgcn_mfma_f32_16x16x32_bf16(a, b, c, 0, 0, 0);
}

union B8 { bf16 h[8]; int4 v; };
union B4 { bf16 h[4]; int2 v; };

#define QK_SCALE_TOT 0.08838834764831845f              /* 0.125 / sqrt(2) */
#define SC2f (QK_SCALE_TOT * 1.4426950408889634f)      /* -> exp2 domain */

// ---------------- cast q,k,v -> bf16 (vectorized, G13) ----------------
__global__ __launch_bounds__(256) void cast3_kernel(
    const float* __restrict__ q, const float* __restrict__ k,
    const float* __restrict__ v, bf16* __restrict__ out)
{
  const float* src = (blockIdx.y == 0) ? q : (blockIdx.y == 1) ? k : v;
  bf16* dst = out + (size_t)blockIdx.y * (4u << 20);
  size_t i = ((size_t)blockIdx.x * 256 + threadIdx.x) * 8;
  float4 a = *(const float4*)(src + i);
  float4 b = *(const float4*)(src + i + 4);
  B8 u;
  u.h[0] = __float2bfloat16(a.x); u.h[1] = __float2bfloat16(a.y);
  u.h[2] = __float2bfloat16(a.z); u.h[3] = __float2bfloat16(a.w);
  u.h[4] = __float2bfloat16(b.x); u.h[5] = __float2bfloat16(b.y);
  u.h[6] = __float2bfloat16(b.z); u.h[7] = __float2bfloat16(b.w);
  *(int4*)(dst + i) = u.v;
}

// ---------------- weight transpose (+ Wo head-merge permutation) ----------------
// z=0..2: dst[n][k] = W[k][n].  z=3: dst[p][k] = Wo[(k&63)*16 + (k>>6)][p]
// so final GEMM's k index = n_head*64 + c matches Oh[bh][l][c] layout.
__global__ __launch_bounds__(256) void wtrans_kernel(
    const float* __restrict__ Wq, const float* __restrict__ Wk,
    const float* __restrict__ Wv, const float* __restrict__ Wo,
    bf16* __restrict__ dstbase)
{
  __shared__ bf16 ld[64][68];
  const int z = blockIdx.z;
  const float* src = (z == 0) ? Wq : (z == 1) ? Wk : (z == 2) ? Wv : Wo;
  bf16* dst = dstbase + (size_t)z * (1u << 20);
  const int k0 = blockIdx.x * 64, n0 = blockIdx.y * 64;
  const int t = threadIdx.x;
  const bool perm = (z == 3);
#pragma unroll
  for (int it = 0; it < 4; ++it) {
    int kk = it * 16 + (t >> 4);
    int K = k0 + kk;
    int j = perm ? ((K & 63) * 16 + (K >> 6)) : K;
    float4 vv = *(const float4*)(src + (size_t)j * 1024 + n0 + (t & 15) * 4);
    int c = (t & 15) * 4;
    ld[c + 0][kk] = __float2bfloat16(vv.x);
    ld[c + 1][kk] = __float2bfloat16(vv.y);
    ld[c + 2][kk] = __float2bfloat16(vv.z);
    ld[c + 3][kk] = __float2bfloat16(vv.w);
  }
  __syncthreads();
#pragma unroll
  for (int it = 0; it < 2; ++it) {
    int rr = it * 32 + (t >> 3), cc = (t & 7) * 8;
    B8 u;
#pragma unroll
    for (int e = 0; e < 8; ++e) u.h[e] = ld[rr][cc + e];
    *(int4*)(dst + (size_t)(n0 + rr) * 1024 + k0 + cc) = u.v;
  }
}

// ---------------- m97-structure 128x128 GEMM, BK=64, 4 waves ----------------
// FINAL=0: grid (8,32,3); A = casted x (row-major), BT = W^T; out head-split.
// FINAL=1: grid (8,32);   A = Oh with head-merge folded into addressing; out fp32.
template<int FINAL>
__global__ __launch_bounds__(256) void gemm_kernel(
    const bf16* __restrict__ Abase, const bf16* __restrict__ WTbase,
    bf16* __restrict__ Qh, bf16* __restrict__ Kh, bf16* __restrict__ VhT,
    float* __restrict__ Cout)
{
  __shared__ bf16 lA[128 * 64];
  __shared__ bf16 lB[128 * 64];
  const int t = threadIdx.x, lane = t & 63;
  const int wv = t >> 6, wr = wv >> 1, wc = wv & 1;
  const int l15 = lane & 15, yi8 = (lane >> 4) * 8;
  const int tN = blockIdx.x * 128, tM = blockIdx.y * 128;
  const int z = FINAL ? 0 : blockIdx.z;

  const bf16* A  = Abase  + (size_t)z * (4u << 20);
  const bf16* BT = WTbase + (size_t)z * (1u << 20);

  const int sr = t >> 3, sc8 = (t & 7) * 8;
  size_t aoff[4], boff[4];
#pragma unroll
  for (int i = 0; i < 4; ++i) {
    int row = tM + i * 32 + sr;
    if (FINAL) {
      // Oh[bh= b*16 + (k>>6)][l][c=k&63]; initial k = sc8 (<64) -> bh = b*16
      aoff[i] = (size_t)(row >> 11) * 16 * (2048 * 64) + (size_t)(row & 2047) * 64 + sc8;
    } else {
      aoff[i] = (size_t)row * 1024 + sc8;
    }
    boff[i] = (size_t)(tN + i * 32 + sr) * 1024 + sc8;
  }
  const size_t astep = FINAL ? (size_t)(2048 * 64) : 64;  // k += 64 each K-tile

  f32x4 acc[4][4];
#pragma unroll
  for (int m = 0; m < 4; ++m)
#pragma unroll
    for (int n = 0; n < 4; ++n) acc[m][n] = {0.f, 0.f, 0.f, 0.f};

  for (int kt = 0; kt < 16; ++kt) {
#pragma unroll
    for (int i = 0; i < 4; ++i) GLD16(A + aoff[i], &lA[i * 2048 + t * 8]);
#pragma unroll
    for (int i = 0; i < 4; ++i) GLD16(BT + boff[i], &lB[i * 2048 + t * 8]);
#pragma unroll
    for (int i = 0; i < 4; ++i) { aoff[i] += astep; boff[i] += 64; }
    __syncthreads();
#pragma unroll
    for (int kk = 0; kk < 2; ++kk) {
      short8 af[4], bfr[4];
#pragma unroll
      for (int m = 0; m < 4; ++m)
        af[m] = *(const short8*)&lA[(wr * 64 + m * 16 + l15) * 64 + kk * 32 + yi8];
#pragma unroll
      for (int n = 0; n < 4; ++n)
        bfr[n] = *(const short8*)&lB[(wc * 64 + n * 16 + l15) * 64 + kk * 32 + yi8];
#pragma unroll
      for (int m = 0; m < 4; ++m)
#pragma unroll
        for (int n = 0; n < 4; ++n)
          acc[m][n] = mfma16(af[m], bfr[n], acc[m][n]);
    }
    __syncthreads();
  }

  // epilogue: D-frag layout col = lane&15, row = (lane>>4)*4 + j  [m89]
#pragma unroll
  for (int m = 0; m < 4; ++m) {
#pragma unroll
    for (int n = 0; n < 4; ++n) {
      int col = tN + wc * 64 + n * 16 + l15;
      int rbase = tM + wr * 64 + m * 16 + (lane >> 4) * 4;
      if (FINAL) {
#pragma unroll
        for (int j = 0; j < 4; ++j)
          Cout[(size_t)(rbase + j) * 1024 + col] = acc[m][n][j];
      } else if (z == 2) {
        // VhT[bh][c][l]; 4 consecutive l -> packed 8B store
        int nh = col & 15, c = col >> 4;
        int b = rbase >> 11, l0 = rbase & 2047;
        B4 u;
#pragma unroll
        for (int j = 0; j < 4; ++j) u.h[j] = __float2bfloat16(acc[m][n][j]);
        *(int2*)&VhT[((size_t)(b * 16 + nh) * 64 + c) * 2048 + l0] = u.v;
      } else {
        bf16* dst = z ? Kh : Qh;  // Qh/Kh[bh][l][c]
        int nh = col & 15, c = col >> 4;
#pragma unroll
        for (int j = 0; j < 4; ++j) {
          int row = rbase + j;
          dst[((size_t)((row >> 11) * 16 + nh) * 2048 + (row & 2047)) * 64 + c] =
              __float2bfloat16(acc[m][n][j]);
        }
      }
    }
  }
}

// ---------------- flash attention: 4 waves x 32 q-rows, KV tiles of 64 ----------------
__global__ __launch_bounds__(256) void attn_kernel(
    const bf16* __restrict__ Qh, const bf16* __restrict__ Kh,
    const bf16* __restrict__ VhT, bf16* __restrict__ Oh)
{
  __shared__ bf16 Kt[64 * 64];        // [kv][c] linear (global_load_lds)
  __shared__ bf16 Vt[64 * 64];        // [c][kv] linear
  __shared__ bf16 Pb[4][32 * 64];     // per-wave P, XOR-swizzled (16-elem granule)
  const int t = threadIdx.x, lane = t & 63, w = t >> 6;
  const int l15 = lane & 15, yi = lane >> 4;
  const int bh = blockIdx.y;
  const int q0 = blockIdx.x * 128 + w * 32;
  const size_t baseQK = (size_t)bh * (2048 * 64);
  const size_t baseV  = (size_t)bh * (64 * 2048);

  // Q fragments in registers (rows q0 + m2*16 + l15, k = kk*32 + yi*8)
  short8 qf[2][2];
#pragma unroll
  for (int m2 = 0; m2 < 2; ++m2)
#pragma unroll
    for (int kk = 0; kk < 2; ++kk)
      qf[m2][kk] = *(const short8*)&Qh[baseQK + (size_t)(q0 + m2 * 16 + l15) * 64 + kk * 32 + yi * 8];

  f32x4 o[2][4];
  float mreg[2][4], lreg[2][4];
#pragma unroll
  for (int m2 = 0; m2 < 2; ++m2) {
#pragma unroll
    for (int nd = 0; nd < 4; ++nd) o[m2][nd] = {0.f, 0.f, 0.f, 0.f};
#pragma unroll
    for (int j = 0; j < 4; ++j) { mreg[m2][j] = -1e30f; lreg[m2][j] = 0.f; }
  }

  const int sr = t >> 3, sc8t = (t & 7) * 8;

  for (int kv0 = 0; kv0 < 2048; kv0 += 64) {
    GLD16(Kh  + baseQK + (size_t)(kv0 + sr) * 64 + sc8t,        &Kt[t * 8]);
    GLD16(Kh  + baseQK + (size_t)(kv0 + 32 + sr) * 64 + sc8t,   &Kt[2048 + t * 8]);
    GLD16(VhT + baseV  + (size_t)sr * 2048 + kv0 + sc8t,        &Vt[t * 8]);
    GLD16(VhT + baseV  + (size_t)(sr + 32) * 2048 + kv0 + sc8t, &Vt[2048 + t * 8]);
    __syncthreads();

    // S = Q . K^T (raw, scale folded into exp2)
    f32x4 s[2][4];
#pragma unroll
    for (int m2 = 0; m2 < 2; ++m2)
#pragma unroll
      for (int nb = 0; nb < 4; ++nb) s[m2][nb] = {0.f, 0.f, 0.f, 0.f};
#pragma unroll
    for (int kk = 0; kk < 2; ++kk) {
      short8 kf[4];
#pragma unroll
      for (int nb = 0; nb < 4; ++nb)
        kf[nb] = *(const short8*)&Kt[(nb * 16 + l15) * 64 + kk * 32 + yi * 8];
#pragma unroll
      for (int m2 = 0; m2 < 2; ++m2)
#pragma unroll
        for (int nb = 0; nb < 4; ++nb)
          s[m2][nb] = mfma16(qf[m2][kk], kf[nb], s[m2][nb]);
    }

    // online softmax per 16x16 row-fragment (rows = yi*4 + j)
#pragma unroll
    for (int m2 = 0; m2 < 2; ++m2) {
      float rmax[4], corr[4], rsum[4], pj[4][4];
#pragma unroll
      for (int j = 0; j < 4; ++j)
        rmax[j] = fmaxf(fmaxf(s[m2][0][j], s[m2][1][j]), fmaxf(s[m2][2][j], s[m2][3][j]));
#pragma unroll
      for (int mk = 1; mk <= 8; mk <<= 1)
#pragma unroll
        for (int j = 0; j < 4; ++j)
          rmax[j] = fmaxf(rmax[j], __shfl_xor(rmax[j], mk));
#pragma unroll
      for (int j = 0; j < 4; ++j) {
        float nm = fmaxf(mreg[m2][j], rmax[j]);
        corr[j] = exp2f((mreg[m2][j] - nm) * SC2f);
        mreg[m2][j] = nm;
        float rs = 0.f;
#pragma unroll
        for (int nb = 0; nb < 4; ++nb) {
          pj[nb][j] = exp2f((s[m2][nb][j] - nm) * SC2f);
          rs += pj[nb][j];
        }
        rsum[j] = rs;
      }
#pragma unroll
      for (int mk = 1; mk <= 8; mk <<= 1)
#pragma unroll
        for (int j = 0; j < 4; ++j)
          rsum[j] += __shfl_xor(rsum[j], mk);
#pragma unroll
      for (int j = 0; j < 4; ++j)
        lreg[m2][j] = lreg[m2][j] * corr[j] + rsum[j];
#pragma unroll
      for (int nd = 0; nd < 4; ++nd)
#pragma unroll
        for (int j = 0; j < 4; ++j) o[m2][nd][j] *= corr[j];
      // P -> LDS (bf16), swizzled: phys_col = col ^ (((row>>2)&3)<<4)
#pragma unroll
      for (int nb = 0; nb < 4; ++nb)
#pragma unroll
        for (int j = 0; j < 4; ++j) {
          int row = m2 * 16 + yi * 4 + j;
          int colp = (nb * 16 + l15) ^ (((row >> 2) & 3) << 4);
          Pb[w][row * 64 + colp] = __float2bfloat16(pj[nb][j]);
        }
    }

    // O += P . V
#pragma unroll
    for (int kk2 = 0; kk2 < 2; ++kk2) {
      short8 pa[2], vf[4];
#pragma unroll
      for (int m2 = 0; m2 < 2; ++m2) {
        int row = m2 * 16 + l15;
        int colc = (kk2 * 32 + yi * 8) ^ (((row >> 2) & 3) << 4);
        pa[m2] = *(const short8*)&Pb[w][row * 64 + colc];
      }
#pragma unroll
      for (int nd = 0; nd < 4; ++nd)
        vf[nd] = *(const short8*)&Vt[(nd * 16 + l15) * 64 + kk2 * 32 + yi * 8];
#pragma unroll
      for (int m2 = 0; m2 < 2; ++m2)
#pragma unroll
        for (int nd = 0; nd < 4; ++nd)
          o[m2][nd] = mfma16(pa[m2], vf[nd], o[m2][nd]);
    }
    __syncthreads();
  }

  // normalize + write Oh[bh][l][c]
#pragma unroll
  for (int m2 = 0; m2 < 2; ++m2)
#pragma unroll
    for (int nd = 0; nd < 4; ++nd) {
      int col = nd * 16 + l15;
#pragma unroll
      for (int j = 0; j < 4; ++j) {
        int row = q0 + m2 * 16 + yi * 4 + j;
        Oh[baseQK + (size_t)row * 64 + col] =
            __float2bfloat16(o[m2][nd][j] / lreg[m2][j]);
      }
    }
}

extern "C" void kernel_launch(void* const* d_in, const int* in_sizes, int n_in,
                              void* d_out, int out_size, void* d_ws, size_t ws_size,
                              hipStream_t stream) {
  const float* q  = (const float*)d_in[0];
  const float* k  = (const float*)d_in[1];
  const float* v  = (const float*)d_in[2];
  const float* Wq = (const float*)d_in[3];
  const float* Wk = (const float*)d_in[4];
  const float* Wv = (const float*)d_in[5];
  const float* Wo = (const float*)d_in[6];
  char* ws = (char*)d_ws;
  const size_t MB = 1u << 20;
  bf16* xb  = (bf16*)(ws);            // 24MB: q,k,v bf16 (dead after proj gemm)
  bf16* WT  = (bf16*)(ws + 24 * MB);  // 8MB: WqT,WkT,WvT,WoT'
  bf16* Qh  = (bf16*)(ws + 32 * MB);  // 8MB
  bf16* Kh  = (bf16*)(ws + 40 * MB);  // 8MB
  bf16* VhT = (bf16*)(ws + 48 * MB);  // 8MB
  bf16* Oh  = (bf16*)(ws);            // 8MB, reuses dead cast region

  cast3_kernel<<<dim3(2048, 3), 256, 0, stream>>>(q, k, v, xb);
  wtrans_kernel<<<dim3(16, 16, 4), 256, 0, stream>>>(Wq, Wk, Wv, Wo, WT);
  gemm_kernel<0><<<dim3(8, 32, 3), 256, 0, stream>>>(xb, WT, Qh, Kh, VhT, nullptr);
  attn_kernel<<<dim3(16, 32), 256, 0, stream>>>(Qh, Kh, VhT, Oh);
  gemm_kernel<1><<<dim3(8, 32), 256, 0, stream>>>(Oh, WT + 3 * (1u << 20), Qh, Kh, VhT,
                                                  (float*)d_out);
}

// Round 2
// 284.616 us; speedup vs baseline: 1.3066x; 1.3066x over previous
//
#include <hip/hip_runtime.h>
#include <hip/hip_bf16.h>

// AttnDecoder: B=2, Lq=Lkv=2048, E=1024, H=16, D=64, scale = 0.125/sqrt(2).
// Pipeline (all bf16 MFMA, fp32 accum):
//   cast3: q,k,v fp32 -> bf16 row-major           [ws +0 .. +24MB]
//   wtrans: Wq,Wk,Wv -> bf16 W^T (N x K); Wo -> permuted W^T folding head-merge [ws +24 .. +32MB]
//   gemm<0> (z=0..2): X @ W -> head-split Qh,Kh [bh][l][c], VhT [bh][c][l] [ws +32 .. +56MB]
//   attn: m214-style 32x32 swapped-QK^T flash attention -> Oh [bh][l][c] [ws +0]
//   gemm<1>: Oh (head-merge folded into A addressing) @ WoT' -> d_out fp32
// Workspace required: 56 MB.

typedef __attribute__((ext_vector_type(8))) short short8;    // 8 x bf16 (4 VGPR)
typedef __attribute__((ext_vector_type(4))) float f32x4;     // 16x16 accumulator
typedef __attribute__((ext_vector_type(16))) float f32x16;   // 32x32 accumulator
typedef __hip_bfloat16 bf16;

#define GLD16(g, l) __builtin_amdgcn_global_load_lds( \
    (const __attribute__((address_space(1))) void*)(g), \
    (__attribute__((address_space(3))) void*)(l), 16, 0, 0)

__device__ __forceinline__ f32x4 mfma16(short8 a, short8 b, f32x4 c) {
  return __builtin_amdgcn_mfma_f32_16x16x32_bf16(a, b, c, 0, 0, 0);
}
__device__ __forceinline__ f32x16 mfma32(short8 a, short8 b, f32x16 c) {
  return __builtin_amdgcn_mfma_f32_32x32x16_bf16(a, b, c, 0, 0, 0);
}

union B8 { bf16 h[8]; int4 v; };
union B4 { bf16 h[4]; int2 v; };

#define QK_SCALE_TOT 0.08838834764831845f              /* 0.125 / sqrt(2) */
#define SC2f (QK_SCALE_TOT * 1.4426950408889634f)      /* -> exp2 domain */

__device__ __forceinline__ float fexp2(float x) {
#if __has_builtin(__builtin_amdgcn_exp2f)
  return __builtin_amdgcn_exp2f(x);
#else
  return exp2f(x);
#endif
}

__device__ __forceinline__ int cvtpk(float lo, float hi_) {
  int r;
  asm("v_cvt_pk_bf16_f32 %0, %1, %2" : "=v"(r) : "v"(lo), "v"(hi_));
  return r;
}

#define ZV16 {0.f,0.f,0.f,0.f,0.f,0.f,0.f,0.f,0.f,0.f,0.f,0.f,0.f,0.f,0.f,0.f}

// ---------------- cast q,k,v -> bf16 (vectorized, G13) ----------------
__global__ __launch_bounds__(256) void cast3_kernel(
    const float* __restrict__ q, const float* __restrict__ k,
    const float* __restrict__ v, bf16* __restrict__ out)
{
  const float* src = (blockIdx.y == 0) ? q : (blockIdx.y == 1) ? k : v;
  bf16* dst = out + (size_t)blockIdx.y * (4u << 20);
  size_t i = ((size_t)blockIdx.x * 256 + threadIdx.x) * 8;
  float4 a = *(const float4*)(src + i);
  float4 b = *(const float4*)(src + i + 4);
  B8 u;
  u.h[0] = __float2bfloat16(a.x); u.h[1] = __float2bfloat16(a.y);
  u.h[2] = __float2bfloat16(a.z); u.h[3] = __float2bfloat16(a.w);
  u.h[4] = __float2bfloat16(b.x); u.h[5] = __float2bfloat16(b.y);
  u.h[6] = __float2bfloat16(b.z); u.h[7] = __float2bfloat16(b.w);
  *(int4*)(dst + i) = u.v;
}

// ---------------- weight transpose (+ Wo head-merge permutation) ----------------
__global__ __launch_bounds__(256) void wtrans_kernel(
    const float* __restrict__ Wq, const float* __restrict__ Wk,
    const float* __restrict__ Wv, const float* __restrict__ Wo,
    bf16* __restrict__ dstbase)
{
  __shared__ bf16 ld[64][68];
  const int z = blockIdx.z;
  const float* src = (z == 0) ? Wq : (z == 1) ? Wk : (z == 2) ? Wv : Wo;
  bf16* dst = dstbase + (size_t)z * (1u << 20);
  const int k0 = blockIdx.x * 64, n0 = blockIdx.y * 64;
  const int t = threadIdx.x;
  const bool perm = (z == 3);
#pragma unroll
  for (int it = 0; it < 4; ++it) {
    int kk = it * 16 + (t >> 4);
    int K = k0 + kk;
    int j = perm ? ((K & 63) * 16 + (K >> 6)) : K;
    float4 vv = *(const float4*)(src + (size_t)j * 1024 + n0 + (t & 15) * 4);
    int c = (t & 15) * 4;
    ld[c + 0][kk] = __float2bfloat16(vv.x);
    ld[c + 1][kk] = __float2bfloat16(vv.y);
    ld[c + 2][kk] = __float2bfloat16(vv.z);
    ld[c + 3][kk] = __float2bfloat16(vv.w);
  }
  __syncthreads();
#pragma unroll
  for (int it = 0; it < 2; ++it) {
    int rr = it * 32 + (t >> 3), cc = (t & 7) * 8;
    B8 u;
#pragma unroll
    for (int e = 0; e < 8; ++e) u.h[e] = ld[rr][cc + e];
    *(int4*)(dst + (size_t)(n0 + rr) * 1024 + k0 + cc) = u.v;
  }
}

// ---------------- m97-structure 128x128 GEMM, BK=64, 4 waves ----------------
template<int FINAL>
__global__ __launch_bounds__(256) void gemm_kernel(
    const bf16* __restrict__ Abase, const bf16* __restrict__ WTbase,
    bf16* __restrict__ Qh, bf16* __restrict__ Kh, bf16* __restrict__ VhT,
    float* __restrict__ Cout)
{
  __shared__ bf16 lA[128 * 64];
  __shared__ bf16 lB[128 * 64];
  const int t = threadIdx.x, lane = t & 63;
  const int wv = t >> 6, wr = wv >> 1, wc = wv & 1;
  const int l15 = lane & 15, yi8 = (lane >> 4) * 8;
  const int tN = blockIdx.x * 128, tM = blockIdx.y * 128;
  const int z = FINAL ? 0 : blockIdx.z;

  const bf16* A  = Abase  + (size_t)z * (4u << 20);
  const bf16* BT = WTbase + (size_t)z * (1u << 20);

  const int sr = t >> 3, sc8 = (t & 7) * 8;
  size_t aoff[4], boff[4];
#pragma unroll
  for (int i = 0; i < 4; ++i) {
    int row = tM + i * 32 + sr;
    if (FINAL) {
      aoff[i] = (size_t)(row >> 11) * 16 * (2048 * 64) + (size_t)(row & 2047) * 64 + sc8;
    } else {
      aoff[i] = (size_t)row * 1024 + sc8;
    }
    boff[i] = (size_t)(tN + i * 32 + sr) * 1024 + sc8;
  }
  const size_t astep = FINAL ? (size_t)(2048 * 64) : 64;

  f32x4 acc[4][4];
#pragma unroll
  for (int m = 0; m < 4; ++m)
#pragma unroll
    for (int n = 0; n < 4; ++n) acc[m][n] = {0.f, 0.f, 0.f, 0.f};

  for (int kt = 0; kt < 16; ++kt) {
#pragma unroll
    for (int i = 0; i < 4; ++i) GLD16(A + aoff[i], &lA[i * 2048 + t * 8]);
#pragma unroll
    for (int i = 0; i < 4; ++i) GLD16(BT + boff[i], &lB[i * 2048 + t * 8]);
#pragma unroll
    for (int i = 0; i < 4; ++i) { aoff[i] += astep; boff[i] += 64; }
    __syncthreads();
#pragma unroll
    for (int kk = 0; kk < 2; ++kk) {
      short8 af[4], bfr[4];
#pragma unroll
      for (int m = 0; m < 4; ++m)
        af[m] = *(const short8*)&lA[(wr * 64 + m * 16 + l15) * 64 + kk * 32 + yi8];
#pragma unroll
      for (int n = 0; n < 4; ++n)
        bfr[n] = *(const short8*)&lB[(wc * 64 + n * 16 + l15) * 64 + kk * 32 + yi8];
#pragma unroll
      for (int m = 0; m < 4; ++m)
#pragma unroll
        for (int n = 0; n < 4; ++n)
          acc[m][n] = mfma16(af[m], bfr[n], acc[m][n]);
    }
    __syncthreads();
  }

#pragma unroll
  for (int m = 0; m < 4; ++m) {
#pragma unroll
    for (int n = 0; n < 4; ++n) {
      int col = tN + wc * 64 + n * 16 + l15;
      int rbase = tM + wr * 64 + m * 16 + (lane >> 4) * 4;
      if (FINAL) {
#pragma unroll
        for (int j = 0; j < 4; ++j)
          Cout[(size_t)(rbase + j) * 1024 + col] = acc[m][n][j];
      } else if (z == 2) {
        int nh = col & 15, c = col >> 4;
        int b = rbase >> 11, l0 = rbase & 2047;
        B4 u;
#pragma unroll
        for (int j = 0; j < 4; ++j) u.h[j] = __float2bfloat16(acc[m][n][j]);
        *(int2*)&VhT[((size_t)(b * 16 + nh) * 64 + c) * 2048 + l0] = u.v;
      } else {
        bf16* dst = z ? Kh : Qh;
        int nh = col & 15, c = col >> 4;
#pragma unroll
        for (int j = 0; j < 4; ++j) {
          int row = rbase + j;
          dst[((size_t)((row >> 11) * 16 + nh) * 2048 + (row & 2047)) * 64 + c] =
              __float2bfloat16(acc[m][n][j]);
        }
      }
    }
  }
}

// ---------------- flash attention, m214 structure ----------------
// 4 waves x 32 q-rows (QBLK=128), KV tiles of 64, 32x32x16 MFMA.
// Swapped QK^T: S^T[kv][q] = mfma(K, Q) -> each lane owns P column q = lane&31.
// Softmax in-register (tree reduce + 1 shfl_xor(32)); P -> PV B-frags via
// cvt_pk_bf16 + permlane32_swap (T12). No LDS P buffer, no ds_write at all.
// K [kv][d] and V^T [d][kv] staged via global_load_lds with source-side XOR
// swizzle (granule ^= row&7); ds_read_b128 uses the same swizzle (rule 21).
__global__ __launch_bounds__(256) void attn_kernel(
    const bf16* __restrict__ Qh, const bf16* __restrict__ Kh,
    const bf16* __restrict__ VhT, bf16* __restrict__ Oh)
{
  __shared__ bf16 Kt[2][64 * 64];
  __shared__ bf16 Vt[2][64 * 64];
  const int t = threadIdx.x, lane = t & 63, w = t >> 6;
  const int l31 = lane & 31, hi = lane >> 5;
  const int bh = blockIdx.y;
  const int q0 = blockIdx.x * 128 + w * 32;
  const size_t baseQK = (size_t)bh * (2048 * 64);
  const size_t baseV  = (size_t)bh * (64 * 2048);

  // Q as B-operand frags: B[row=d][col=q]; lane holds col=l31, rows hi*8+e
  short8 qf[4];
#pragma unroll
  for (int kc = 0; kc < 4; ++kc)
    qf[kc] = *(const short8*)&Qh[baseQK + (size_t)(q0 + l31) * 64 + kc * 16 + hi * 8];

  // staging: 512 granules/tile/buffer; thread t covers granules t and t+256.
  // source granule = logical ^ (row&7)  (row&7 identical for both rounds)
  const int r0 = t >> 3, g0 = t & 7;
  const int sg = (g0 ^ (r0 & 7)) * 8;          // elem offset within row
  const bf16* ksrc0 = Kh  + baseQK + (size_t)r0 * 64 + sg;
  const bf16* ksrc1 = Kh  + baseQK + (size_t)(r0 + 32) * 64 + sg;
  const bf16* vsrc0 = VhT + baseV  + (size_t)r0 * 2048 + sg;
  const bf16* vsrc1 = VhT + baseV  + (size_t)(r0 + 32) * 2048 + sg;

  auto stage = [&](int buf, int ti) {
    GLD16(ksrc0 + (size_t)ti * 4096, &Kt[buf][t * 8]);
    GLD16(ksrc1 + (size_t)ti * 4096, &Kt[buf][2048 + t * 8]);
    GLD16(vsrc0 + ti * 64,           &Vt[buf][t * 8]);
    GLD16(vsrc1 + ti * 64,           &Vt[buf][2048 + t * 8]);
  };

  f32x16 o0 = ZV16, o1 = ZV16;
  float m = -1e30f, l = 0.f;
  const int swz = (l31 & 7);  // read-side granule swizzle

  stage(0, 0);
  for (int ti = 0; ti < 32; ++ti) {
    const int buf = ti & 1;
    __syncthreads();                    // drains vmcnt -> buf ready
    if (ti < 31) stage(buf ^ 1, ti + 1);

    // ---- S^T = K . Q^T : rows kv (2 blocks of 32), cols q ----
    f32x16 s0 = ZV16, s1 = ZV16;
    __builtin_amdgcn_s_setprio(1);
#pragma unroll
    for (int kc = 0; kc < 4; ++kc) {
      const int gr = ((kc * 2 + hi) ^ swz) * 8;
      short8 kf0 = *(const short8*)&Kt[buf][l31 * 64 + gr];
      short8 kf1 = *(const short8*)&Kt[buf][(32 + l31) * 64 + gr];
      s0 = mfma32(kf0, qf[kc], s0);
      s1 = mfma32(kf1, qf[kc], s1);
    }
    __builtin_amdgcn_s_setprio(0);

    // ---- online softmax, fully in-register (column q = l31 per lane) ----
    float tm8[8];
#pragma unroll
    for (int i2 = 0; i2 < 8; ++i2)
      tm8[i2] = fmaxf(fmaxf(s0[i2], s0[i2 + 8]), fmaxf(s1[i2], s1[i2 + 8]));
    float pm = fmaxf(fmaxf(fmaxf(tm8[0], tm8[1]), fmaxf(tm8[2], tm8[3])),
                     fmaxf(fmaxf(tm8[4], tm8[5]), fmaxf(tm8[6], tm8[7])));
    pm = fmaxf(pm, __shfl_xor(pm, 32));
    float mn = fmaxf(m, pm);
    float corr = fexp2((m - mn) * SC2f);
    m = mn;
    float nb = -mn * SC2f;
#pragma unroll
    for (int r = 0; r < 16; ++r) {
      s0[r] = fexp2(s0[r] * SC2f + nb);
      s1[r] = fexp2(s1[r] * SC2f + nb);
    }
    float ts8[8];
#pragma unroll
    for (int i2 = 0; i2 < 8; ++i2)
      ts8[i2] = (s0[i2] + s0[i2 + 8]) + (s1[i2] + s1[i2 + 8]);
    float rs = ((ts8[0] + ts8[1]) + (ts8[2] + ts8[3])) +
               ((ts8[4] + ts8[5]) + (ts8[6] + ts8[7]));
    rs += __shfl_xor(rs, 32);
    l = l * corr + rs;
#pragma unroll
    for (int r = 0; r < 16; ++r) { o0[r] *= corr; o1[r] *= corr; }

    // ---- P (f32, kv-rows in regs) -> bf16 B-frags via cvt_pk + permlane ----
    // p[r] holds kv = kb*32 + (r&3) + 8*(r>>2) + 4*hi ; frag kc needs rows
    // kc*16 + hi*8 + e.  swap(w[j], w[j+2]) -> (low word, high word). [T12]
    short8 pf[4];
    {
      union U { int i[4]; short8 s8; } fr[4];
      int wds[16];
#pragma unroll
      for (int j = 0; j < 8; ++j) wds[j]     = cvtpk(s0[2 * j], s0[2 * j + 1]);
#pragma unroll
      for (int j = 0; j < 8; ++j) wds[8 + j] = cvtpk(s1[2 * j], s1[2 * j + 1]);
#pragma unroll
      for (int fb = 0; fb < 4; ++fb) {  // frag fb built from wds[fb*4 .. fb*4+3]
        int a0 = wds[fb * 4 + 0], a1 = wds[fb * 4 + 1];
        int a2 = wds[fb * 4 + 2], a3 = wds[fb * 4 + 3];
#if __has_builtin(__builtin_amdgcn_permlane32_swap)
        auto s02 = __builtin_amdgcn_permlane32_swap(a0, a2, false, false);
        auto s13 = __builtin_amdgcn_permlane32_swap(a1, a3, false, false);
        fr[fb].i[0] = s02[0]; fr[fb].i[1] = s13[0];
        fr[fb].i[2] = s02[1]; fr[fb].i[3] = s13[1];
#else
        int x0 = __shfl_xor(a0, 32), x2 = __shfl_xor(a2, 32);
        int x1 = __shfl_xor(a1, 32), x3 = __shfl_xor(a3, 32);
        fr[fb].i[0] = hi ? x2 : a0; fr[fb].i[1] = hi ? x3 : a1;
        fr[fb].i[2] = hi ? a2 : x0; fr[fb].i[3] = hi ? a3 : x1;
#endif
        pf[fb] = fr[fb].s8;
      }
    }

    // ---- O^T += V^T . P^T : rows d (2 blocks of 32), cols q ----
    __builtin_amdgcn_s_setprio(1);
#pragma unroll
    for (int kc = 0; kc < 4; ++kc) {
      const int gr = ((kc * 2 + hi) ^ swz) * 8;
      short8 vf0 = *(const short8*)&Vt[buf][l31 * 64 + gr];
      short8 vf1 = *(const short8*)&Vt[buf][(32 + l31) * 64 + gr];
      o0 = mfma32(vf0, pf[kc], o0);
      o1 = mfma32(vf1, pf[kc], o1);
    }
    __builtin_amdgcn_s_setprio(0);
  }

  // ---- normalize + write Oh[bh][l][d]; rows d = (r&3)+8*(r>>2)+4*hi (+32) ----
  float rl = 1.0f / l;
  bf16* orow = Oh + baseQK + (size_t)(q0 + l31) * 64;
#pragma unroll
  for (int rq = 0; rq < 4; ++rq) {
    B4 u0, u1;
#pragma unroll
    for (int j = 0; j < 4; ++j) {
      u0.h[j] = __float2bfloat16(o0[rq * 4 + j] * rl);
      u1.h[j] = __float2bfloat16(o1[rq * 4 + j] * rl);
    }
    int dbase = rq * 8 + hi * 4;
    *(int2*)&orow[dbase]      = u0.v;
    *(int2*)&orow[32 + dbase] = u1.v;
  }
}

extern "C" void kernel_launch(void* const* d_in, const int* in_sizes, int n_in,
                              void* d_out, int out_size, void* d_ws, size_t ws_size,
                              hipStream_t stream) {
  const float* q  = (const float*)d_in[0];
  const float* k  = (const float*)d_in[1];
  const float* v  = (const float*)d_in[2];
  const float* Wq = (const float*)d_in[3];
  const float* Wk = (const float*)d_in[4];
  const float* Wv = (const float*)d_in[5];
  const float* Wo = (const float*)d_in[6];
  char* ws = (char*)d_ws;
  const size_t MB = 1u << 20;
  bf16* xb  = (bf16*)(ws);            // 24MB: q,k,v bf16 (dead after proj gemm)
  bf16* WT  = (bf16*)(ws + 24 * MB);  // 8MB: WqT,WkT,WvT,WoT'
  bf16* Qh  = (bf16*)(ws + 32 * MB);  // 8MB
  bf16* Kh  = (bf16*)(ws + 40 * MB);  // 8MB
  bf16* VhT = (bf16*)(ws + 48 * MB);  // 8MB
  bf16* Oh  = (bf16*)(ws);            // 8MB, reuses dead cast region

  cast3_kernel<<<dim3(2048, 3), 256, 0, stream>>>(q, k, v, xb);
  wtrans_kernel<<<dim3(16, 16, 4), 256, 0, stream>>>(Wq, Wk, Wv, Wo, WT);
  gemm_kernel<0><<<dim3(8, 32, 3), 256, 0, stream>>>(xb, WT, Qh, Kh, VhT, nullptr);
  attn_kernel<<<dim3(16, 32), 256, 0, stream>>>(Qh, Kh, VhT, Oh);
  gemm_kernel<1><<<dim3(8, 32), 256, 0, stream>>>(Oh, WT + 3 * (1u << 20), Qh, Kh, VhT,
                                                  (float*)d_out);
}